// Round 5
// baseline (689.126 us; speedup 1.0000x reference)
//
#include <hip/hip_runtime.h>
#include <hip/hip_bf16.h>

// ============================================================================
// ROUND 5 = ATTRIBUTION PROBE. k_linear compute x8, k_attn main loop x4
// (idempotent repeats). dur_us is intentionally inflated; purpose is to get
// per-kernel durations + counters into rocprof's top-5 (cutoff ~161us fills).
// Revert kRepLin/kRepAttn to 1 to recover the fast kernel.
// ============================================================================

namespace {
constexpr int kN    = 8192;
constexpr int kFin  = 512;
constexpr int kFout = 64;
constexpr float kAlpha = 0.2f;
constexpr int kJSplit = 8;                  // j-range split for k_attn (wave-level)
constexpr int kJLen   = kN / kJSplit;       // 1024 j per wave
constexpr int kChunks = kJLen / 32;         // 32 chunks of 32 j
constexpr int kTileParts = 2;               // accp partials per 16-row tile
constexpr int kRepLin  = 8;                 // PROBE: k_linear compute repeats
constexpr int kRepAttn = 4;                 // PROBE: k_attn main-loop repeats

using bf16x4 = __attribute__((ext_vector_type(4))) short;
using bf16x8 = __attribute__((ext_vector_type(8))) short;
using f32x4  = __attribute__((ext_vector_type(4))) float;

__device__ __forceinline__ unsigned short f2bf(float x) {
  return __builtin_bit_cast(unsigned short, __float2bfloat16(x));
}
__device__ __forceinline__ float lrelu(float x) {
  return fmaxf(x, kAlpha * x);   // valid since 0<alpha<1
}
// monotone float<->uint order-preserving map (for atomicMax on float)
__device__ __forceinline__ unsigned int fkey(float x) {
  unsigned int b = __float_as_uint(x);
  return (b & 0x80000000u) ? ~b : (b | 0x80000000u);
}
__device__ __forceinline__ float fdec(unsigned int k) {
  return (k & 0x80000000u) ? __uint_as_float(k ^ 0x80000000u) : __uint_as_float(~k);
}
} // namespace

// ---------------------------------------------------------------------------
// k_wt (unchanged r9): k-packed W layout WT2[(k/4)*256 + f*4 + (k%4)].
// ---------------------------------------------------------------------------
__global__ __launch_bounds__(256) void k_wt(const float* __restrict__ W,
                                            float* __restrict__ WT2,
                                            unsigned int* __restrict__ Smax_u) {
  const int gid = blockIdx.x * 256 + threadIdx.x;   // 0..32767
  if (gid == 0) *Smax_u = 0u;                       // < fkey(any finite)
  const int k = gid >> 6, f = gid & 63;
  WT2[(k >> 2) * 256 + f * 4 + (k & 3)] = W[gid];
}

// ---------------------------------------------------------------------------
// k_linear (r9 + PROBE x8 repeat of everything after the X staging).
// Repeats are idempotent: same stores, atomicMax of same value, accumulators
// re-zeroed. Trailing __syncthreads per rep prevents h_sm WAR across reps.
// FETCH is NOT multiplied (X staged once) -> probe isolates compute cost.
// ---------------------------------------------------------------------------
__global__ __launch_bounds__(256) void k_linear(
    const float* __restrict__ X, const float* __restrict__ WT2, const float* __restrict__ A,
    unsigned short* __restrict__ hTf, float* __restrict__ s_src, float* __restrict__ s_dst,
    unsigned int* __restrict__ Smax_u)
{
  const int t = threadIdx.x;
  const int wv = t >> 6, f = t & 63;
  const int i0 = blockIdx.x * 16;

  __shared__ float Xlds[16 * kFin];          // 32 KB
  __shared__ unsigned short h_sm[16][64];    // 2 KB
  __shared__ float red[4];

  // ---- bulk-stage X tile: 8 outstanding float4 per thread (ONCE) ----
  {
    const float4* Xg = (const float4*)(X + (size_t)i0 * kFin);
    float4* Xl = (float4*)Xlds;
    float4 v0 = Xg[t +   0], v1 = Xg[t + 256], v2 = Xg[t +  512], v3 = Xg[t +  768];
    float4 v4 = Xg[t +1024], v5 = Xg[t +1280], v6 = Xg[t + 1536], v7 = Xg[t + 1792];
    Xl[t +    0] = v0; Xl[t +  256] = v1; Xl[t +  512] = v2; Xl[t +  768] = v3;
    Xl[t + 1024] = v4; Xl[t + 1280] = v5; Xl[t + 1536] = v6; Xl[t + 1792] = v7;
  }
  __syncthreads();

  const int r0l = wv * 4;                    // local row base
  const float4* wp = (const float4*)WT2 + f; // k-packed W stream
  const float* xr = Xlds + r0l * kFin;
  const float asrc = A[f], adst = A[kFout + f];

#pragma unroll 1
  for (int rep = 0; rep < kRepLin; ++rep) {
    asm volatile("" ::: "memory");           // forbid cross-rep CSE

    float acc0 = 0.f, acc1 = 0.f, acc2 = 0.f, acc3 = 0.f;
    float4 wb0 = wp[0];
    float4 wb1 = wp[64];
    for (int k = 0; k < kFin; k += 4) {
      const float4 wc = (k & 4) ? wb1 : wb0;
      if (k + 8 < kFin) {
        const float4 wn = wp[(size_t)(k + 8) * 16];   // ((k+8)/4)*64
        if (k & 4) wb1 = wn; else wb0 = wn;
      }
      const float4 xa = *(const float4*)(xr + k);
      const float4 xb = *(const float4*)(xr + kFin + k);
      const float4 xc = *(const float4*)(xr + 2 * kFin + k);
      const float4 xd = *(const float4*)(xr + 3 * kFin + k);
#pragma unroll
      for (int j = 0; j < 4; ++j) {
        const float wk = ((const float*)&wc)[j];
        acc0 = fmaf(((const float*)&xa)[j], wk, acc0);
        acc1 = fmaf(((const float*)&xb)[j], wk, acc1);
        acc2 = fmaf(((const float*)&xc)[j], wk, acc2);
        acc3 = fmaf(((const float*)&xd)[j], wk, acc3);
      }
    }

    // ---- scores + per-wave s_dst max ----
    float accs[4] = {acc0, acc1, acc2, acc3};
    float dmax = -3.4e38f;
#pragma unroll
    for (int r = 0; r < 4; ++r) {
      float vs = accs[r] * asrc;
      float vd = accs[r] * adst;
#pragma unroll
      for (int off = 32; off > 0; off >>= 1) {
        vs += __shfl_xor(vs, off, 64);
        vd += __shfl_xor(vd, off, 64);
      }
      if (f == 0) {
        s_src[i0 + r0l + r] = vs;
        s_dst[i0 + r0l + r] = vd;
        dmax = fmaxf(dmax, vd);
      }
      h_sm[r0l + r][f] = f2bf(accs[r]);
    }
    if (f == 0) red[wv] = dmax;
    __syncthreads();
    if (t == 0) {
      float m = fmaxf(fmaxf(red[0], red[1]), fmaxf(red[2], red[3]));
      atomicMax(Smax_u, fkey(m));
    }

    // ---- emit 2 KB hTf fragment slice, coalesced ----
    if (t < 128) {
      const int jblk = i0 >> 5, half = (i0 >> 4) & 1;
      const int w = t >> 5, li = t & 31;
      const int lane = half * 32 + li;
      const int ql = li >> 4, fcol = w * 16 + (li & 15);
      bf16x8 v;
#pragma unroll
      for (int e = 0; e < 8; ++e) v[e] = (short)h_sm[ql * 8 + e][fcol];
      *(bf16x8*)(hTf + (size_t)jblk * 2048 + w * 512 + (size_t)lane * 8) = v;
    }
    __syncthreads();   // protect h_sm against next rep's writes
  }
}

// ---------------------------------------------------------------------------
// k_attn (r8 structure + PROBE x4 repeat of the main loop).
// Each rep re-streams adj from HBM (268 MB > 256 MB L3 -> real re-reads),
// preserving the memory-bound character. Accumulators re-zeroed per rep;
// wrap-around prefetch leaves chunk-0/1 registers primed for the next rep.
// ---------------------------------------------------------------------------
__global__ __launch_bounds__(256, 4) void k_attn(
    const int* __restrict__ adj, const unsigned short* __restrict__ hTf,
    const float* __restrict__ s_src, const float* __restrict__ s_dst,
    const unsigned int* __restrict__ Smax_u, float* __restrict__ accp,
    float* __restrict__ lp)
{
  const int t = threadIdx.x;
  const int wv = t >> 6, lane = t & 63;
  const int wid = blockIdx.x * 4 + wv;             // 0..4095
  const int tile = wid >> 3;                       // 0..511 (16-row tile)
  const int q    = wid & 7;                        // j-octant
  const int i0 = tile * 16, jbase = q * kJLen;
  // load-layout coords
  const int lr = lane >> 3;                        // row within half (0-7)
  const int lg = lane & 7;                         // 4-col group
  // fragment-layout coords
  const int row = lane & 15, quad = lane >> 4;

  __shared__ unsigned short Pl[4][2][16][40];      // 10 KB (padded rows, 80 B)
  __shared__ float sacc[4][16][64];                // 16 KB
  __shared__ float sl[4][16];                      // 256 B

  const float S = fdec(*Smax_u);
  const float sA = s_src[i0 + lr];
  const float sB = s_src[i0 + 8 + lr];
  const float mA = lrelu(sA + S);                  // >= every score in row lr
  const float mB = lrelu(sB + S);

  // per-lane streams (load layout): 8 int4 per row-chunk
  const int4* aA = (const int4*)(adj + (size_t)(i0 + lr) * kN + jbase) + lg;
  const int4* aB = (const int4*)(adj + (size_t)(i0 + 8 + lr) * kN + jbase) + lg;
  const float4* dp = (const float4*)(s_dst + jbase) + lg;
  const unsigned short* hbase = hTf + (size_t)(jbase >> 5) * 2048 + (size_t)lane * 8;

  float l_accA = 0.f, l_accB = 0.f;
  f32x4 acc0 = {0.f, 0.f, 0.f, 0.f};
  f32x4 acc1 = {0.f, 0.f, 0.f, 0.f};
  f32x4 acc2 = {0.f, 0.f, 0.f, 0.f};
  f32x4 acc3 = {0.f, 0.f, 0.f, 0.f};

  // depth-2 prefetch, named registers
  int4   Aa = aA[0], Ba = aB[0];  float4 Da = dp[0];
  int4   Ab = aA[8], Bb = aB[8];  float4 Db = dp[8];

  auto body = [&](int c, int sbuf, int4& A, int4& B, float4& D)
      __attribute__((always_inline)) {
    // B-fragments for this chunk (L2-resident; issued early, used at MFMA)
    const unsigned short* hp = hbase + (size_t)c * 2048;
    const uint4 hv0 = *(const uint4*)(hp +    0);
    const uint4 hv1 = *(const uint4*)(hp +  512);
    const uint4 hv2 = *(const uint4*)(hp + 1024);
    const uint4 hv3 = *(const uint4*)(hp + 1536);

    // P in load layout: 4 cols of row lr (A) and row 8+lr (B)
    float pvA[4], pvB[4];
    {
      const int*   ia = (const int*)&A;
      const int*   ib = (const int*)&B;
      const float* dd = (const float*)&D;
#pragma unroll
      for (int j = 0; j < 4; ++j) {
        const float eA = lrelu(sA + dd[j]);
        const float eB = lrelu(sB + dd[j]);
        pvA[j] = ia[j] > 0 ? __expf(eA - mA) : 0.f;
        pvB[j] = ib[j] > 0 ? __expf(eB - mB) : 0.f;
      }
    }
    l_accA += (pvA[0] + pvA[1]) + (pvA[2] + pvA[3]);
    l_accB += (pvB[0] + pvB[1]) + (pvB[2] + pvB[3]);

    // pack + route through per-wave LDS (write 8 B x2, conflict-benign)
    bf16x4 wA, wB;
#pragma unroll
    for (int j = 0; j < 4; ++j) {
      wA[j] = (short)f2bf(pvA[j]);
      wB[j] = (short)f2bf(pvB[j]);
    }
    *(bf16x4*)&Pl[wv][sbuf][lr][lg * 4]     = wA;
    *(bf16x4*)&Pl[wv][sbuf][8 + lr][lg * 4] = wB;

    // depth-2 rotate: prefetch chunk c+2 (wrap primes next rep's chunks 0/1)
    {
      const int cn = (c + 2) & (kChunks - 1);
      A = aA[cn * 8];  B = aB[cn * 8];  D = dp[cn * 8];
    }

    // fragment read (16-B aligned, padded stride) + MFMA cluster
    const bf16x8 pa = *(const bf16x8*)&Pl[wv][sbuf][row][quad * 8];
    __builtin_amdgcn_s_setprio(1);
    acc0 = __builtin_amdgcn_mfma_f32_16x16x32_bf16(pa, __builtin_bit_cast(bf16x8, hv0), acc0, 0, 0, 0);
    acc1 = __builtin_amdgcn_mfma_f32_16x16x32_bf16(pa, __builtin_bit_cast(bf16x8, hv1), acc1, 0, 0, 0);
    acc2 = __builtin_amdgcn_mfma_f32_16x16x32_bf16(pa, __builtin_bit_cast(bf16x8, hv2), acc2, 0, 0, 0);
    acc3 = __builtin_amdgcn_mfma_f32_16x16x32_bf16(pa, __builtin_bit_cast(bf16x8, hv3), acc3, 0, 0, 0);
    __builtin_amdgcn_s_setprio(0);
  };

#pragma unroll 1
  for (int rep = 0; rep < kRepAttn; ++rep) {
    asm volatile("" ::: "memory");           // forbid cross-rep CSE
    l_accA = 0.f; l_accB = 0.f;
    acc0 = {0.f, 0.f, 0.f, 0.f};
    acc1 = {0.f, 0.f, 0.f, 0.f};
    acc2 = {0.f, 0.f, 0.f, 0.f};
    acc3 = {0.f, 0.f, 0.f, 0.f};
    for (int c = 0; c < kChunks; c += 2) {
      body(c,     0, Aa, Ba, Da);
      body(c + 1, 1, Ab, Bb, Db);
    }
  }

  // denominator: reduce over the 8 col-groups (lanes sharing lr)
  l_accA += __shfl_xor(l_accA, 1, 64);
  l_accA += __shfl_xor(l_accA, 2, 64);
  l_accA += __shfl_xor(l_accA, 4, 64);
  l_accB += __shfl_xor(l_accB, 1, 64);
  l_accB += __shfl_xor(l_accB, 2, 64);
  l_accB += __shfl_xor(l_accB, 4, 64);
  if (lg == 0) {
    sl[wv][lr]     = l_accA;
    sl[wv][8 + lr] = l_accB;
  }

  // stage this wave's PV tile: [i_local = quad*4+reg][f = g*16+row]
  {
    float* ab = &sacc[wv][0][0];
#pragma unroll
    for (int reg = 0; reg < 4; ++reg) {
      ab[(quad * 4 + reg) * 64 +  0 + row] = acc0[reg];
      ab[(quad * 4 + reg) * 64 + 16 + row] = acc1[reg];
      ab[(quad * 4 + reg) * 64 + 32 + row] = acc2[reg];
      ab[(quad * 4 + reg) * 64 + 48 + row] = acc3[reg];
    }
  }
  __syncthreads();   // post-loop only

  // cross-wave reduce (4 partials) and single coalesced store per block
  {
    const float* sb = &sacc[0][0][0];
    float* gout = accp + (size_t)blockIdx.x * 16 * 64;
#pragma unroll
    for (int k = 0; k < 4; ++k) {
      const int idx = t + k * 256;
      gout[idx] = (sb[idx] + sb[1024 + idx]) + (sb[2048 + idx] + sb[3072 + idx]);
    }
    if (t < 16) {
      lp[(size_t)blockIdx.x * 16 + t] =
          (sl[0][t] + sl[1][t]) + (sl[2][t] + sl[3][t]);
    }
  }
}

// ---------------------------------------------------------------------------
// k_comb: out[i][f] = elu( (sum_p accp) / (sum_p lp) ), 2 partials per tile
// ---------------------------------------------------------------------------
__global__ __launch_bounds__(256) void k_comb(const float* __restrict__ accp,
                                              const float* __restrict__ lp,
                                              float* __restrict__ out)
{
  const int gid = blockIdx.x * 256 + threadIdx.x;   // 0..524287
  const int i = gid >> 6, f = gid & 63;
  const int ib = i >> 4, il = i & 15;
  const int b0 = ib * kTileParts;
  float a = 0.f, l = 0.f;
#pragma unroll
  for (int p = 0; p < kTileParts; ++p) {
    a += accp[((size_t)(b0 + p) * 16 + il) * 64 + f];
    l += lp[(size_t)(b0 + p) * 16 + il];
  }
  float v = a / l;
  v = v > 0.f ? v : __expf(v) - 1.f;
  out[gid] = v;
}

extern "C" void kernel_launch(void* const* d_in, const int* in_sizes, int n_in,
                              void* d_out, int out_size, void* d_ws, size_t ws_size,
                              hipStream_t stream) {
  const float* X   = (const float*)d_in[0];   // [8192][512]
  const int*   adj = (const int*)d_in[1];     // [8192][8192]
  const float* W   = (const float*)d_in[2];   // [512][64]
  const float* A   = (const float*)d_in[3];   // [128]
  float* out = (float*)d_out;                 // [8192][64] fp32

  char* ws = (char*)d_ws;
  unsigned short* hTf = (unsigned short*)ws;  ws += (size_t)kN * kFout * 2;    // 1 MB
  float* WT2   = (float*)ws;                  ws += (size_t)kFout * kFin * 4;  // 128 KB
  float* s_src = (float*)ws;                  ws += kN * 4;
  float* s_dst = (float*)ws;                  ws += kN * 4;
  unsigned int* Smax_u = (unsigned int*)ws;   ws += 256;
  float* accp  = (float*)ws;                  ws += (size_t)(kN / 16) * kTileParts * 16 * 64 * 4; // 4 MB
  float* lp    = (float*)ws;                  // 64 KB

  k_wt    <<<kFin * kFout / 256, 256, 0, stream>>>(W, WT2, Smax_u);
  k_linear<<<kN / 16, 256, 0, stream>>>(X, WT2, A, hTf, s_src, s_dst, Smax_u);
  k_attn  <<<(kN / 16) * kJSplit / 4, 256, 0, stream>>>(adj, hTf, s_src, s_dst, Smax_u, accp, lp);
  k_comb  <<<kN * kFout / 256, 256, 0, stream>>>(accp, lp, out);
}

// Round 6
// 627.752 us; speedup vs baseline: 1.0978x; 1.0978x over previous
//
#include <hip/hip_runtime.h>
#include <hip/hip_bf16.h>

namespace {
constexpr int kN    = 8192;
constexpr int kFin  = 512;
constexpr int kFout = 64;
constexpr float kAlpha = 0.2f;
constexpr int kJSplit = 16;                 // j-range split (wave-level)
constexpr int kJLen   = kN / kJSplit;       // 512 j per wave
constexpr int kChunks = kJLen / 32;         // 16 chunks of 32 j
constexpr int kTileParts = 4;               // accp partials per 16-row tile

using bf16x4 = __attribute__((ext_vector_type(4))) short;
using bf16x8 = __attribute__((ext_vector_type(8))) short;
using f32x4  = __attribute__((ext_vector_type(4))) float;

__device__ __forceinline__ unsigned short f2bf(float x) {
  return __builtin_bit_cast(unsigned short, __float2bfloat16(x));
}
__device__ __forceinline__ float lrelu(float x) {
  return fmaxf(x, kAlpha * x);   // valid since 0<alpha<1
}
// monotone float<->uint order-preserving map (for atomicMax on float)
__device__ __forceinline__ unsigned int fkey(float x) {
  unsigned int b = __float_as_uint(x);
  return (b & 0x80000000u) ? ~b : (b | 0x80000000u);
}
__device__ __forceinline__ float fdec(unsigned int k) {
  return (k & 0x80000000u) ? __uint_as_float(k ^ 0x80000000u) : __uint_as_float(~k);
}
} // namespace

// ---------------------------------------------------------------------------
// k_wt: k-packed W layout WT2[(k/4)*256 + f*4 + (k%4)] (coalesced W stream in
// k_linear). Thread 0 zero-inits the s_dst-max atomic slot.
// ---------------------------------------------------------------------------
__global__ __launch_bounds__(256) void k_wt(const float* __restrict__ W,
                                            float* __restrict__ WT2,
                                            unsigned int* __restrict__ Smax_u) {
  const int gid = blockIdx.x * 256 + threadIdx.x;   // 0..32767
  if (gid == 0) *Smax_u = 0u;                       // < fkey(any finite)
  const int k = gid >> 6, f = gid & 63;
  WT2[(k >> 2) * 256 + f * 4 + (k & 3)] = W[gid];
}

// ---------------------------------------------------------------------------
// k_linear: h = X@W (fp32); s_src/s_dst (+ global max of s_dst via atomicMax);
// h emitted as hTf in MFMA-B-fragment order. grid 512 x 256.
// (Probe-attributed at ~12 us — not the bottleneck; unchanged.)
// ---------------------------------------------------------------------------
__global__ __launch_bounds__(256) void k_linear(
    const float* __restrict__ X, const float* __restrict__ WT2, const float* __restrict__ A,
    unsigned short* __restrict__ hTf, float* __restrict__ s_src, float* __restrict__ s_dst,
    unsigned int* __restrict__ Smax_u)
{
  const int t = threadIdx.x;
  const int wv = t >> 6, f = t & 63;
  const int i0 = blockIdx.x * 16;

  __shared__ float Xlds[16 * kFin];          // 32 KB
  __shared__ unsigned short h_sm[16][64];    // 2 KB
  __shared__ float red[4];

  // ---- bulk-stage X tile: 8 outstanding float4 per thread ----
  {
    const float4* Xg = (const float4*)(X + (size_t)i0 * kFin);
    float4* Xl = (float4*)Xlds;
    float4 v0 = Xg[t +   0], v1 = Xg[t + 256], v2 = Xg[t +  512], v3 = Xg[t +  768];
    float4 v4 = Xg[t +1024], v5 = Xg[t +1280], v6 = Xg[t + 1536], v7 = Xg[t + 1792];
    Xl[t +    0] = v0; Xl[t +  256] = v1; Xl[t +  512] = v2; Xl[t +  768] = v3;
    Xl[t + 1024] = v4; Xl[t + 1280] = v5; Xl[t + 1536] = v6; Xl[t + 1792] = v7;
  }
  __syncthreads();

  const int r0l = wv * 4;                    // local row base
  const float4* wp = (const float4*)WT2 + f; // k-packed W stream
  const float* xr = Xlds + r0l * kFin;
  float acc0 = 0.f, acc1 = 0.f, acc2 = 0.f, acc3 = 0.f;
  float4 wb0 = wp[0];
  float4 wb1 = wp[64];
  for (int k = 0; k < kFin; k += 4) {
    const float4 wc = (k & 4) ? wb1 : wb0;
    if (k + 8 < kFin) {
      const float4 wn = wp[(size_t)(k + 8) * 16];   // ((k+8)/4)*64
      if (k & 4) wb1 = wn; else wb0 = wn;
    }
    const float4 xa = *(const float4*)(xr + k);
    const float4 xb = *(const float4*)(xr + kFin + k);
    const float4 xc = *(const float4*)(xr + 2 * kFin + k);
    const float4 xd = *(const float4*)(xr + 3 * kFin + k);
#pragma unroll
    for (int j = 0; j < 4; ++j) {
      const float wk = ((const float*)&wc)[j];
      acc0 = fmaf(((const float*)&xa)[j], wk, acc0);
      acc1 = fmaf(((const float*)&xb)[j], wk, acc1);
      acc2 = fmaf(((const float*)&xc)[j], wk, acc2);
      acc3 = fmaf(((const float*)&xd)[j], wk, acc3);
    }
  }

  // ---- scores + per-wave s_dst max ----
  const float asrc = A[f], adst = A[kFout + f];
  float accs[4] = {acc0, acc1, acc2, acc3};
  float dmax = -3.4e38f;
#pragma unroll
  for (int r = 0; r < 4; ++r) {
    float vs = accs[r] * asrc;
    float vd = accs[r] * adst;
#pragma unroll
    for (int off = 32; off > 0; off >>= 1) {
      vs += __shfl_xor(vs, off, 64);
      vd += __shfl_xor(vd, off, 64);
    }
    if (f == 0) {
      s_src[i0 + r0l + r] = vs;
      s_dst[i0 + r0l + r] = vd;
      dmax = fmaxf(dmax, vd);
    }
    h_sm[r0l + r][f] = f2bf(accs[r]);
  }
  if (f == 0) red[wv] = dmax;
  __syncthreads();
  if (t == 0) {
    float m = fmaxf(fmaxf(red[0], red[1]), fmaxf(red[2], red[3]));
    atomicMax(Smax_u, fkey(m));
  }

  // ---- emit 2 KB hTf fragment slice, coalesced ----
  if (t < 128) {
    const int jblk = i0 >> 5, half = (i0 >> 4) & 1;
    const int w = t >> 5, li = t & 31;
    const int lane = half * 32 + li;
    const int ql = li >> 4, fcol = w * 16 + (li & 15);
    bf16x8 v;
#pragma unroll
    for (int e = 0; e < 8; ++e) v[e] = (short)h_sm[ql * 8 + e][fcol];
    *(bf16x8*)(hTf + (size_t)jblk * 2048 + w * 512 + (size_t)lane * 8) = v;
  }
}

// ---------------------------------------------------------------------------
// k_attn (r11): r8 structure at 2x occupancy.
// Probe (round 5) showed: 58 us/rep, 37.6% occupancy, nothing saturated ->
// latency-bound. Changes:
//  * kJSplit 8 -> 16 (512-j segments), grid 2048 = 8 blocks/CU,
//    __launch_bounds__(256,8) -> 32 waves/CU (was 16). VGPR was 52 <= 64.
//  * LDS: per-wave 4160-B slots unioning Pl (2560 B, main loop) with the
//    wave's sacc tile (4096 B) + sl (64 B), both post-loop. Same-wave DS
//    ordering makes the overlay safe (last ds_read of Pl precedes the
//    dependent sacc ds_writes). 16.6 KB/block -> LDS no longer caps occupancy.
// ---------------------------------------------------------------------------
__global__ __launch_bounds__(256, 8) void k_attn(
    const int* __restrict__ adj, const unsigned short* __restrict__ hTf,
    const float* __restrict__ s_src, const float* __restrict__ s_dst,
    const unsigned int* __restrict__ Smax_u, float* __restrict__ accp,
    float* __restrict__ lp)
{
  const int t = threadIdx.x;
  const int wv = t >> 6, lane = t & 63;
  const int wid = blockIdx.x * 4 + wv;             // 0..8191
  const int tile = wid >> 4;                       // 0..511 (16-row tile)
  const int seg  = wid & 15;                       // j-segment
  const int i0 = tile * 16, jbase = seg * kJLen;
  // load-layout coords
  const int lr = lane >> 3;                        // row within half (0-7)
  const int lg = lane & 7;                         // 4-col group
  // fragment-layout coords
  const int row = lane & 15, quad = lane >> 4;

  // per-wave 4160-B slot: [0,2560) Pl[2][16][40] | post-loop: [0,4096) sacc,
  // [4096,4160) sl
  __shared__ __align__(16) char smem[4 * 4160];    // 16.6 KB
  char* slot = smem + wv * 4160;
  unsigned short (*Plw)[16][40] = (unsigned short (*)[16][40])slot;

  const float S = fdec(*Smax_u);
  const float sA = s_src[i0 + lr];
  const float sB = s_src[i0 + 8 + lr];
  const float mA = lrelu(sA + S);                  // >= every score in row lr
  const float mB = lrelu(sB + S);

  // per-lane streams (load layout): 8 int4 per row-chunk
  const int4* aA = (const int4*)(adj + (size_t)(i0 + lr) * kN + jbase) + lg;
  const int4* aB = (const int4*)(adj + (size_t)(i0 + 8 + lr) * kN + jbase) + lg;
  const float4* dp = (const float4*)(s_dst + jbase) + lg;
  const unsigned short* hbase = hTf + (size_t)(jbase >> 5) * 2048 + (size_t)lane * 8;

  float l_accA = 0.f, l_accB = 0.f;
  f32x4 acc0 = {0.f, 0.f, 0.f, 0.f};
  f32x4 acc1 = {0.f, 0.f, 0.f, 0.f};
  f32x4 acc2 = {0.f, 0.f, 0.f, 0.f};
  f32x4 acc3 = {0.f, 0.f, 0.f, 0.f};

  // depth-2 prefetch, named registers
  int4   Aa = aA[0], Ba = aB[0];  float4 Da = dp[0];
  int4   Ab = aA[8], Bb = aB[8];  float4 Db = dp[8];

  auto body = [&](int c, int sbuf, int4& A, int4& B, float4& D)
      __attribute__((always_inline)) {
    // B-fragments for this chunk (L2-resident; issued early, used at MFMA)
    const unsigned short* hp = hbase + (size_t)c * 2048;
    const uint4 hv0 = *(const uint4*)(hp +    0);
    const uint4 hv1 = *(const uint4*)(hp +  512);
    const uint4 hv2 = *(const uint4*)(hp + 1024);
    const uint4 hv3 = *(const uint4*)(hp + 1536);

    // P in load layout: 4 cols of row lr (A) and row 8+lr (B)
    float pvA[4], pvB[4];
    {
      const int*   ia = (const int*)&A;
      const int*   ib = (const int*)&B;
      const float* dd = (const float*)&D;
#pragma unroll
      for (int j = 0; j < 4; ++j) {
        const float eA = lrelu(sA + dd[j]);
        const float eB = lrelu(sB + dd[j]);
        pvA[j] = ia[j] > 0 ? __expf(eA - mA) : 0.f;
        pvB[j] = ib[j] > 0 ? __expf(eB - mB) : 0.f;
      }
    }
    l_accA += (pvA[0] + pvA[1]) + (pvA[2] + pvA[3]);
    l_accB += (pvB[0] + pvB[1]) + (pvB[2] + pvB[3]);

    // pack + route through per-wave LDS (write 8 B x2)
    bf16x4 wA, wB;
#pragma unroll
    for (int j = 0; j < 4; ++j) {
      wA[j] = (short)f2bf(pvA[j]);
      wB[j] = (short)f2bf(pvB[j]);
    }
    *(bf16x4*)&Plw[sbuf][lr][lg * 4]     = wA;
    *(bf16x4*)&Plw[sbuf][8 + lr][lg * 4] = wB;

    // depth-2 rotate: prefetch chunk c+2 (wrap harmless)
    {
      const int cn = (c + 2) & (kChunks - 1);
      A = aA[cn * 8];  B = aB[cn * 8];  D = dp[cn * 8];
    }

    // fragment read (16-B aligned, padded stride) + MFMA cluster
    const bf16x8 pa = *(const bf16x8*)&Plw[sbuf][row][quad * 8];
    __builtin_amdgcn_s_setprio(1);
    acc0 = __builtin_amdgcn_mfma_f32_16x16x32_bf16(pa, __builtin_bit_cast(bf16x8, hv0), acc0, 0, 0, 0);
    acc1 = __builtin_amdgcn_mfma_f32_16x16x32_bf16(pa, __builtin_bit_cast(bf16x8, hv1), acc1, 0, 0, 0);
    acc2 = __builtin_amdgcn_mfma_f32_16x16x32_bf16(pa, __builtin_bit_cast(bf16x8, hv2), acc2, 0, 0, 0);
    acc3 = __builtin_amdgcn_mfma_f32_16x16x32_bf16(pa, __builtin_bit_cast(bf16x8, hv3), acc3, 0, 0, 0);
    __builtin_amdgcn_s_setprio(0);
  };

  for (int c = 0; c < kChunks; c += 2) {
    body(c,     0, Aa, Ba, Da);
    body(c + 1, 1, Ab, Bb, Db);
  }

  // denominator: reduce over the 8 col-groups (lanes sharing lr)
  l_accA += __shfl_xor(l_accA, 1, 64);
  l_accA += __shfl_xor(l_accA, 2, 64);
  l_accA += __shfl_xor(l_accA, 4, 64);
  l_accB += __shfl_xor(l_accB, 1, 64);
  l_accB += __shfl_xor(l_accB, 2, 64);
  l_accB += __shfl_xor(l_accB, 4, 64);
  if (lg == 0) {
    float* slw = (float*)(slot + 4096);
    slw[lr]     = l_accA;
    slw[8 + lr] = l_accB;
  }

  // stage this wave's PV tile into its slot (overlays its own dead Pl):
  // [i_local = quad*4+reg][f = g*16+row]
  {
    float* ab = (float*)slot;
#pragma unroll
    for (int reg = 0; reg < 4; ++reg) {
      ab[(quad * 4 + reg) * 64 +  0 + row] = acc0[reg];
      ab[(quad * 4 + reg) * 64 + 16 + row] = acc1[reg];
      ab[(quad * 4 + reg) * 64 + 32 + row] = acc2[reg];
      ab[(quad * 4 + reg) * 64 + 48 + row] = acc3[reg];
    }
  }
  __syncthreads();   // post-loop only

  // cross-wave reduce (4 partials) and single coalesced store per block
  {
    float* gout = accp + (size_t)blockIdx.x * 16 * 64;
#pragma unroll
    for (int k = 0; k < 4; ++k) {
      const int idx = t + k * 256;
      float s = 0.f;
#pragma unroll
      for (int w = 0; w < 4; ++w) s += ((const float*)(smem + w * 4160))[idx];
      gout[idx] = s;
    }
    if (t < 16) {
      float s = 0.f;
#pragma unroll
      for (int w = 0; w < 4; ++w) s += ((const float*)(smem + w * 4160 + 4096))[t];
      lp[(size_t)blockIdx.x * 16 + t] = s;
    }
  }
}

// ---------------------------------------------------------------------------
// k_comb: out[i][f] = elu( (sum_p accp) / (sum_p lp) ), 4 partials per tile
// ---------------------------------------------------------------------------
__global__ __launch_bounds__(256) void k_comb(const float* __restrict__ accp,
                                              const float* __restrict__ lp,
                                              float* __restrict__ out)
{
  const int gid = blockIdx.x * 256 + threadIdx.x;   // 0..524287
  const int i = gid >> 6, f = gid & 63;
  const int ib = i >> 4, il = i & 15;
  const int b0 = ib * kTileParts;
  float a = 0.f, l = 0.f;
#pragma unroll
  for (int p = 0; p < kTileParts; ++p) {
    a += accp[((size_t)(b0 + p) * 16 + il) * 64 + f];
    l += lp[(size_t)(b0 + p) * 16 + il];
  }
  float v = a / l;
  v = v > 0.f ? v : __expf(v) - 1.f;
  out[gid] = v;
}

extern "C" void kernel_launch(void* const* d_in, const int* in_sizes, int n_in,
                              void* d_out, int out_size, void* d_ws, size_t ws_size,
                              hipStream_t stream) {
  const float* X   = (const float*)d_in[0];   // [8192][512]
  const int*   adj = (const int*)d_in[1];     // [8192][8192]
  const float* W   = (const float*)d_in[2];   // [512][64]
  const float* A   = (const float*)d_in[3];   // [128]
  float* out = (float*)d_out;                 // [8192][64] fp32

  char* ws = (char*)d_ws;
  unsigned short* hTf = (unsigned short*)ws;  ws += (size_t)kN * kFout * 2;    // 1 MB
  float* WT2   = (float*)ws;                  ws += (size_t)kFout * kFin * 4;  // 128 KB
  float* s_src = (float*)ws;                  ws += kN * 4;
  float* s_dst = (float*)ws;                  ws += kN * 4;
  unsigned int* Smax_u = (unsigned int*)ws;   ws += 256;
  float* accp  = (float*)ws;                  ws += (size_t)(kN / 16) * kTileParts * 16 * 64 * 4; // 8 MB
  float* lp    = (float*)ws;                  // 128 KB

  k_wt    <<<kFin * kFout / 256, 256, 0, stream>>>(W, WT2, Smax_u);
  k_linear<<<kN / 16, 256, 0, stream>>>(X, WT2, A, hTf, s_src, s_dst, Smax_u);
  k_attn  <<<(kN / 16) * kTileParts, 256, 0, stream>>>(adj, hTf, s_src, s_dst, Smax_u, accp, lp);
  k_comb  <<<kN * kFout / 256, 256, 0, stream>>>(accp, lp, out);
}

// Round 7
// 424.028 us; speedup vs baseline: 1.6252x; 1.4804x over previous
//
#include <hip/hip_runtime.h>
#include <hip/hip_bf16.h>

namespace {
constexpr int kN    = 8192;
constexpr int kFin  = 512;
constexpr int kFout = 64;
constexpr float kAlpha = 0.2f;
constexpr int kJSplit = 16;                 // j-range split (wave-level)
constexpr int kJLen   = kN / kJSplit;       // 512 j per wave
constexpr int kChunks = kJLen / 32;         // 16 chunks of 32 j
constexpr int kTileParts = 4;               // accp partials per 16-row tile

using bf16x4 = __attribute__((ext_vector_type(4))) short;
using bf16x8 = __attribute__((ext_vector_type(8))) short;
using f32x4  = __attribute__((ext_vector_type(4))) float;

__device__ __forceinline__ unsigned short f2bf(float x) {
  return __builtin_bit_cast(unsigned short, __float2bfloat16(x));
}
__device__ __forceinline__ float lrelu(float x) {
  return fmaxf(x, kAlpha * x);   // valid since 0<alpha<1
}
// monotone float<->uint order-preserving map (for atomicMax on float)
__device__ __forceinline__ unsigned int fkey(float x) {
  unsigned int b = __float_as_uint(x);
  return (b & 0x80000000u) ? ~b : (b | 0x80000000u);
}
__device__ __forceinline__ float fdec(unsigned int k) {
  return (k & 0x80000000u) ? __uint_as_float(k ^ 0x80000000u) : __uint_as_float(~k);
}
} // namespace

// ---------------------------------------------------------------------------
// k_wt: k-packed W layout WT2[(k/4)*256 + f*4 + (k%4)] (coalesced W stream in
// k_linear). Thread 0 zero-inits the s_dst-max atomic slot.
// ---------------------------------------------------------------------------
__global__ __launch_bounds__(256) void k_wt(const float* __restrict__ W,
                                            float* __restrict__ WT2,
                                            unsigned int* __restrict__ Smax_u) {
  const int gid = blockIdx.x * 256 + threadIdx.x;   // 0..32767
  if (gid == 0) *Smax_u = 0u;                       // < fkey(any finite)
  const int k = gid >> 6, f = gid & 63;
  WT2[(k >> 2) * 256 + f * 4 + (k & 3)] = W[gid];
}

// ---------------------------------------------------------------------------
// k_linear: h = X@W (fp32); s_src/s_dst (+ global max of s_dst via atomicMax);
// h emitted as hTf in MFMA-B-fragment order. grid 512 x 256.
// (Probe-attributed at ~12 us — not the bottleneck; unchanged.)
// ---------------------------------------------------------------------------
__global__ __launch_bounds__(256) void k_linear(
    const float* __restrict__ X, const float* __restrict__ WT2, const float* __restrict__ A,
    unsigned short* __restrict__ hTf, float* __restrict__ s_src, float* __restrict__ s_dst,
    unsigned int* __restrict__ Smax_u)
{
  const int t = threadIdx.x;
  const int wv = t >> 6, f = t & 63;
  const int i0 = blockIdx.x * 16;

  __shared__ float Xlds[16 * kFin];          // 32 KB
  __shared__ unsigned short h_sm[16][64];    // 2 KB
  __shared__ float red[4];

  // ---- bulk-stage X tile: 8 outstanding float4 per thread ----
  {
    const float4* Xg = (const float4*)(X + (size_t)i0 * kFin);
    float4* Xl = (float4*)Xlds;
    float4 v0 = Xg[t +   0], v1 = Xg[t + 256], v2 = Xg[t +  512], v3 = Xg[t +  768];
    float4 v4 = Xg[t +1024], v5 = Xg[t +1280], v6 = Xg[t + 1536], v7 = Xg[t + 1792];
    Xl[t +    0] = v0; Xl[t +  256] = v1; Xl[t +  512] = v2; Xl[t +  768] = v3;
    Xl[t + 1024] = v4; Xl[t + 1280] = v5; Xl[t + 1536] = v6; Xl[t + 1792] = v7;
  }
  __syncthreads();

  const int r0l = wv * 4;                    // local row base
  const float4* wp = (const float4*)WT2 + f; // k-packed W stream
  const float* xr = Xlds + r0l * kFin;
  float acc0 = 0.f, acc1 = 0.f, acc2 = 0.f, acc3 = 0.f;
  float4 wb0 = wp[0];
  float4 wb1 = wp[64];
  for (int k = 0; k < kFin; k += 4) {
    const float4 wc = (k & 4) ? wb1 : wb0;
    if (k + 8 < kFin) {
      const float4 wn = wp[(size_t)(k + 8) * 16];   // ((k+8)/4)*64
      if (k & 4) wb1 = wn; else wb0 = wn;
    }
    const float4 xa = *(const float4*)(xr + k);
    const float4 xb = *(const float4*)(xr + kFin + k);
    const float4 xc = *(const float4*)(xr + 2 * kFin + k);
    const float4 xd = *(const float4*)(xr + 3 * kFin + k);
#pragma unroll
    for (int j = 0; j < 4; ++j) {
      const float wk = ((const float*)&wc)[j];
      acc0 = fmaf(((const float*)&xa)[j], wk, acc0);
      acc1 = fmaf(((const float*)&xb)[j], wk, acc1);
      acc2 = fmaf(((const float*)&xc)[j], wk, acc2);
      acc3 = fmaf(((const float*)&xd)[j], wk, acc3);
    }
  }

  // ---- scores + per-wave s_dst max ----
  const float asrc = A[f], adst = A[kFout + f];
  float accs[4] = {acc0, acc1, acc2, acc3};
  float dmax = -3.4e38f;
#pragma unroll
  for (int r = 0; r < 4; ++r) {
    float vs = accs[r] * asrc;
    float vd = accs[r] * adst;
#pragma unroll
    for (int off = 32; off > 0; off >>= 1) {
      vs += __shfl_xor(vs, off, 64);
      vd += __shfl_xor(vd, off, 64);
    }
    if (f == 0) {
      s_src[i0 + r0l + r] = vs;
      s_dst[i0 + r0l + r] = vd;
      dmax = fmaxf(dmax, vd);
    }
    h_sm[r0l + r][f] = f2bf(accs[r]);
  }
  if (f == 0) red[wv] = dmax;
  __syncthreads();
  if (t == 0) {
    float m = fmaxf(fmaxf(red[0], red[1]), fmaxf(red[2], red[3]));
    atomicMax(Smax_u, fkey(m));
  }

  // ---- emit 2 KB hTf fragment slice, coalesced ----
  if (t < 128) {
    const int jblk = i0 >> 5, half = (i0 >> 4) & 1;
    const int w = t >> 5, li = t & 31;
    const int lane = half * 32 + li;
    const int ql = li >> 4, fcol = w * 16 + (li & 15);
    bf16x8 v;
#pragma unroll
    for (int e = 0; e < 8; ++e) v[e] = (short)h_sm[ql * 8 + e][fcol];
    *(bf16x8*)(hTf + (size_t)jblk * 2048 + w * 512 + (size_t)lane * 8) = v;
  }
}

// ---------------------------------------------------------------------------
// k_attn (r12): r11 structure, launch_bounds back to (256,4).
// Round 6 post-mortem: (256,8) capped VGPR at 32 -> ~500 MB scratch spill
// traffic (WRITE_SIZE 511 MB), dur 314 us. The 2nd launch_bounds arg is an
// allocator GUARANTEE, not an occupancy cap: at VGPR=52 (<=64, the 8-waves/
// SIMD threshold) and LDS 16.9 KB (<= 160KB/8), the 2048-block grid still
// reaches 8 blocks/CU = 32 waves/CU without forcing spills.
// ---------------------------------------------------------------------------
__global__ __launch_bounds__(256, 4) void k_attn(
    const int* __restrict__ adj, const unsigned short* __restrict__ hTf,
    const float* __restrict__ s_src, const float* __restrict__ s_dst,
    const unsigned int* __restrict__ Smax_u, float* __restrict__ accp,
    float* __restrict__ lp)
{
  const int t = threadIdx.x;
  const int wv = t >> 6, lane = t & 63;
  const int wid = blockIdx.x * 4 + wv;             // 0..8191
  const int tile = wid >> 4;                       // 0..511 (16-row tile)
  const int seg  = wid & 15;                       // j-segment
  const int i0 = tile * 16, jbase = seg * kJLen;
  // load-layout coords
  const int lr = lane >> 3;                        // row within half (0-7)
  const int lg = lane & 7;                         // 4-col group
  // fragment-layout coords
  const int row = lane & 15, quad = lane >> 4;

  // per-wave 4160-B slot: [0,2560) Pl[2][16][40] | post-loop: [0,4096) sacc,
  // [4096,4160) sl
  __shared__ __align__(16) char smem[4 * 4160];    // 16.6 KB
  char* slot = smem + wv * 4160;
  unsigned short (*Plw)[16][40] = (unsigned short (*)[16][40])slot;

  const float S = fdec(*Smax_u);
  const float sA = s_src[i0 + lr];
  const float sB = s_src[i0 + 8 + lr];
  const float mA = lrelu(sA + S);                  // >= every score in row lr
  const float mB = lrelu(sB + S);

  // per-lane streams (load layout): 8 int4 per row-chunk
  const int4* aA = (const int4*)(adj + (size_t)(i0 + lr) * kN + jbase) + lg;
  const int4* aB = (const int4*)(adj + (size_t)(i0 + 8 + lr) * kN + jbase) + lg;
  const float4* dp = (const float4*)(s_dst + jbase) + lg;
  const unsigned short* hbase = hTf + (size_t)(jbase >> 5) * 2048 + (size_t)lane * 8;

  float l_accA = 0.f, l_accB = 0.f;
  f32x4 acc0 = {0.f, 0.f, 0.f, 0.f};
  f32x4 acc1 = {0.f, 0.f, 0.f, 0.f};
  f32x4 acc2 = {0.f, 0.f, 0.f, 0.f};
  f32x4 acc3 = {0.f, 0.f, 0.f, 0.f};

  // depth-2 prefetch, named registers
  int4   Aa = aA[0], Ba = aB[0];  float4 Da = dp[0];
  int4   Ab = aA[8], Bb = aB[8];  float4 Db = dp[8];

  auto body = [&](int c, int sbuf, int4& A, int4& B, float4& D)
      __attribute__((always_inline)) {
    // B-fragments for this chunk (L2-resident; issued early, used at MFMA)
    const unsigned short* hp = hbase + (size_t)c * 2048;
    const uint4 hv0 = *(const uint4*)(hp +    0);
    const uint4 hv1 = *(const uint4*)(hp +  512);
    const uint4 hv2 = *(const uint4*)(hp + 1024);
    const uint4 hv3 = *(const uint4*)(hp + 1536);

    // P in load layout: 4 cols of row lr (A) and row 8+lr (B)
    float pvA[4], pvB[4];
    {
      const int*   ia = (const int*)&A;
      const int*   ib = (const int*)&B;
      const float* dd = (const float*)&D;
#pragma unroll
      for (int j = 0; j < 4; ++j) {
        const float eA = lrelu(sA + dd[j]);
        const float eB = lrelu(sB + dd[j]);
        pvA[j] = ia[j] > 0 ? __expf(eA - mA) : 0.f;
        pvB[j] = ib[j] > 0 ? __expf(eB - mB) : 0.f;
      }
    }
    l_accA += (pvA[0] + pvA[1]) + (pvA[2] + pvA[3]);
    l_accB += (pvB[0] + pvB[1]) + (pvB[2] + pvB[3]);

    // pack + route through per-wave LDS (write 8 B x2)
    bf16x4 wA, wB;
#pragma unroll
    for (int j = 0; j < 4; ++j) {
      wA[j] = (short)f2bf(pvA[j]);
      wB[j] = (short)f2bf(pvB[j]);
    }
    *(bf16x4*)&Plw[sbuf][lr][lg * 4]     = wA;
    *(bf16x4*)&Plw[sbuf][8 + lr][lg * 4] = wB;

    // depth-2 rotate: prefetch chunk c+2 (wrap harmless)
    {
      const int cn = (c + 2) & (kChunks - 1);
      A = aA[cn * 8];  B = aB[cn * 8];  D = dp[cn * 8];
    }

    // fragment read (16-B aligned, padded stride) + MFMA cluster
    const bf16x8 pa = *(const bf16x8*)&Plw[sbuf][row][quad * 8];
    __builtin_amdgcn_s_setprio(1);
    acc0 = __builtin_amdgcn_mfma_f32_16x16x32_bf16(pa, __builtin_bit_cast(bf16x8, hv0), acc0, 0, 0, 0);
    acc1 = __builtin_amdgcn_mfma_f32_16x16x32_bf16(pa, __builtin_bit_cast(bf16x8, hv1), acc1, 0, 0, 0);
    acc2 = __builtin_amdgcn_mfma_f32_16x16x32_bf16(pa, __builtin_bit_cast(bf16x8, hv2), acc2, 0, 0, 0);
    acc3 = __builtin_amdgcn_mfma_f32_16x16x32_bf16(pa, __builtin_bit_cast(bf16x8, hv3), acc3, 0, 0, 0);
    __builtin_amdgcn_s_setprio(0);
  };

  for (int c = 0; c < kChunks; c += 2) {
    body(c,     0, Aa, Ba, Da);
    body(c + 1, 1, Ab, Bb, Db);
  }

  // denominator: reduce over the 8 col-groups (lanes sharing lr)
  l_accA += __shfl_xor(l_accA, 1, 64);
  l_accA += __shfl_xor(l_accA, 2, 64);
  l_accA += __shfl_xor(l_accA, 4, 64);
  l_accB += __shfl_xor(l_accB, 1, 64);
  l_accB += __shfl_xor(l_accB, 2, 64);
  l_accB += __shfl_xor(l_accB, 4, 64);
  if (lg == 0) {
    float* slw = (float*)(slot + 4096);
    slw[lr]     = l_accA;
    slw[8 + lr] = l_accB;
  }

  // stage this wave's PV tile into its slot (overlays its own dead Pl):
  // [i_local = quad*4+reg][f = g*16+row]
  {
    float* ab = (float*)slot;
#pragma unroll
    for (int reg = 0; reg < 4; ++reg) {
      ab[(quad * 4 + reg) * 64 +  0 + row] = acc0[reg];
      ab[(quad * 4 + reg) * 64 + 16 + row] = acc1[reg];
      ab[(quad * 4 + reg) * 64 + 32 + row] = acc2[reg];
      ab[(quad * 4 + reg) * 64 + 48 + row] = acc3[reg];
    }
  }
  __syncthreads();   // post-loop only

  // cross-wave reduce (4 partials) and single coalesced store per block
  {
    float* gout = accp + (size_t)blockIdx.x * 16 * 64;
#pragma unroll
    for (int k = 0; k < 4; ++k) {
      const int idx = t + k * 256;
      float s = 0.f;
#pragma unroll
      for (int w = 0; w < 4; ++w) s += ((const float*)(smem + w * 4160))[idx];
      gout[idx] = s;
    }
    if (t < 16) {
      float s = 0.f;
#pragma unroll
      for (int w = 0; w < 4; ++w) s += ((const float*)(smem + w * 4160 + 4096))[t];
      lp[(size_t)blockIdx.x * 16 + t] = s;
    }
  }
}

// ---------------------------------------------------------------------------
// k_comb: out[i][f] = elu( (sum_p accp) / (sum_p lp) ), 4 partials per tile
// ---------------------------------------------------------------------------
__global__ __launch_bounds__(256) void k_comb(const float* __restrict__ accp,
                                              const float* __restrict__ lp,
                                              float* __restrict__ out)
{
  const int gid = blockIdx.x * 256 + threadIdx.x;   // 0..524287
  const int i = gid >> 6, f = gid & 63;
  const int ib = i >> 4, il = i & 15;
  const int b0 = ib * kTileParts;
  float a = 0.f, l = 0.f;
#pragma unroll
  for (int p = 0; p < kTileParts; ++p) {
    a += accp[((size_t)(b0 + p) * 16 + il) * 64 + f];
    l += lp[(size_t)(b0 + p) * 16 + il];
  }
  float v = a / l;
  v = v > 0.f ? v : __expf(v) - 1.f;
  out[gid] = v;
}

extern "C" void kernel_launch(void* const* d_in, const int* in_sizes, int n_in,
                              void* d_out, int out_size, void* d_ws, size_t ws_size,
                              hipStream_t stream) {
  const float* X   = (const float*)d_in[0];   // [8192][512]
  const int*   adj = (const int*)d_in[1];     // [8192][8192]
  const float* W   = (const float*)d_in[2];   // [512][64]
  const float* A   = (const float*)d_in[3];   // [128]
  float* out = (float*)d_out;                 // [8192][64] fp32

  char* ws = (char*)d_ws;
  unsigned short* hTf = (unsigned short*)ws;  ws += (size_t)kN * kFout * 2;    // 1 MB
  float* WT2   = (float*)ws;                  ws += (size_t)kFout * kFin * 4;  // 128 KB
  float* s_src = (float*)ws;                  ws += kN * 4;
  float* s_dst = (float*)ws;                  ws += kN * 4;
  unsigned int* Smax_u = (unsigned int*)ws;   ws += 256;
  float* accp  = (float*)ws;                  ws += (size_t)(kN / 16) * kTileParts * 16 * 64 * 4; // 8 MB
  float* lp    = (float*)ws;                  // 128 KB

  k_wt    <<<kFin * kFout / 256, 256, 0, stream>>>(W, WT2, Smax_u);
  k_linear<<<kN / 16, 256, 0, stream>>>(X, WT2, A, hTf, s_src, s_dst, Smax_u);
  k_attn  <<<(kN / 16) * kTileParts, 256, 0, stream>>>(adj, hTf, s_src, s_dst, Smax_u, accp, lp);
  k_comb  <<<kN * kFout / 256, 256, 0, stream>>>(accp, lp, out);
}